// Round 14
// baseline (728.989 us; speedup 1.0000x reference)
//
#include <hip/hip_runtime.h>
#include <hip/hip_fp16.h>

#define N_NODES 50000
#define N_EDGES 1600000
#define H 64
#define IN_CH 7
#define EDIM 4
#define G_GRAPHS 256
#define FC 128
#define NC 2
#define SLOPE 0.2f
#define BSH 6                           // bucket shift: 64 nodes per bucket
#define BNODES 64
#define NBUCK ((N_NODES + BNODES - 1) / BNODES)    // 782
#define EPB1 8192                       // edges per front hist block
#define NB1 ((N_EDGES + EPB1 - 1) / EPB1)          // 196
#define PAIR_BLOCKS ((N_NODES * 32 + 255) / 256)   // 6250

typedef _Float16 h2v __attribute__((ext_vector_type(2)));

__device__ __forceinline__ float fdot2f(h2v a, h2v b, float c) {
#if defined(__has_builtin) && __has_builtin(__builtin_amdgcn_fdot2)
    return __builtin_amdgcn_fdot2(a, b, c, false);
#else
    return c + (float)a[0] * (float)b[0] + (float)a[1] * (float)b[1];
#endif
}

// ---------------- DPP wave-64 reductions ----------------
__device__ __forceinline__ float wave_sum_to63(float x) {
    x += __int_as_float(__builtin_amdgcn_update_dpp(0, __float_as_int(x), 0x111, 0xf, 0xf, true)); // row_shr:1
    x += __int_as_float(__builtin_amdgcn_update_dpp(0, __float_as_int(x), 0x112, 0xf, 0xf, true)); // row_shr:2
    x += __int_as_float(__builtin_amdgcn_update_dpp(0, __float_as_int(x), 0x114, 0xf, 0xf, true)); // row_shr:4
    x += __int_as_float(__builtin_amdgcn_update_dpp(0, __float_as_int(x), 0x118, 0xf, 0xf, true)); // row_shr:8
    x += __int_as_float(__builtin_amdgcn_update_dpp(0, __float_as_int(x), 0x142, 0xf, 0xf, true)); // row_bcast:15
    x += __int_as_float(__builtin_amdgcn_update_dpp(0, __float_as_int(x), 0x143, 0xf, 0xf, true)); // row_bcast:31
    return x;
}
__device__ __forceinline__ float lane63_bcast(float x) {
    return __int_as_float(__builtin_amdgcn_readlane(__float_as_int(x), 63));
}

// ---------------- fused front-end: bucket histogram (LDS + global flush) + proj0 + prep ----------------
__global__ __launch_bounds__(256) void front_kernel(
        const int* __restrict__ dst, int* __restrict__ bcnt,
        const float* __restrict__ xin,
        const float* __restrict__ Wl0, const float* __restrict__ bl0,
        const float* __restrict__ Wr0, const float* __restrict__ br0,
        __half2* __restrict__ xlh, __half2* __restrict__ xrh,
        const float* __restrict__ We0, const float* __restrict__ We1,
        const float* __restrict__ Wl1, const float* __restrict__ bl1,
        const float* __restrict__ Wr1, const float* __restrict__ br1,
        __half2* __restrict__ weh0, __half2* __restrict__ weh1,
        __half2* __restrict__ wt, float* __restrict__ bb,
        const float* __restrict__ att0, const float* __restrict__ att1,
        __half2* __restrict__ atth0, __half2* __restrict__ atth1) {
    __shared__ int hist[NBUCK];
    int b = blockIdx.x;
    int t = threadIdx.x;
    if (b < NB1) {
        for (int i = t; i < NBUCK; i += 256) hist[i] = 0;
        __syncthreads();
#pragma unroll
        for (int i = 0; i < EPB1 / 256; ++i) {
            int e = b * EPB1 + i * 256 + t;
            if (e < N_EDGES)
                atomicAdd(&hist[dst[e] >> BSH], 1);
        }
        __syncthreads();
        for (int i = t; i < NBUCK; i += 256) {
            int v = hist[i];
            if (v) atomicAdd(&bcnt[i], v);
        }
    } else if (b < NB1 + PAIR_BLOCKS) {
        int idx = (b - NB1) * 256 + t;
        if (idx < N_NODES * 32) {
            int n = idx >> 5;
            int c = idx & 31;
            const float* xi = xin + n * IN_CH;
            float2 bl2 = ((const float2*)bl0)[c];
            float2 br2 = ((const float2*)br0)[c];
            float al0 = bl2.x, al1 = bl2.y, ar0 = br2.x, ar1 = br2.y;
#pragma unroll
            for (int k = 0; k < IN_CH; ++k) {
                float xv = xi[k];
                float2 wl2 = ((const float2*)(Wl0 + k * H))[c];
                float2 wr2 = ((const float2*)(Wr0 + k * H))[c];
                al0 += xv * wl2.x; al1 += xv * wl2.y;
                ar0 += xv * wr2.x; ar1 += xv * wr2.y;
            }
            xlh[idx] = __floats2half2_rn(al0, al1);
            xrh[idx] = __floats2half2_rn(ar0, ar1);
        }
    } else {
        if (t < 32) {
            for (int k = 0; k < 4; ++k)
                weh0[t * 4 + k] = __floats2half2_rn(We0[k * H + 2 * t], We0[k * H + 2 * t + 1]);
        } else if (t < 64) {
            int c = t - 32;
            for (int k = 0; k < 4; ++k)
                weh1[c * 4 + k] = __floats2half2_rn(We1[k * H + 2 * c], We1[k * H + 2 * c + 1]);
        }
        if (t < 128) {
            const float* W = (t < 64) ? Wl1 : Wr1;
            int c = t & 63;
            for (int kk = 0; kk < 32; ++kk)
                wt[t * 32 + kk] = __floats2half2_rn(W[(2 * kk) * H + c], W[(2 * kk + 1) * H + c]);
            bb[t] = (t < 64) ? bl1[c] : br1[c];
        } else if (t < 160) {
            int c = t - 128;
            atth0[c] = __floats2half2_rn(att0[2 * c], att0[2 * c + 1]);
            atth1[c] = __floats2half2_rn(att1[2 * c], att1[2 * c + 1]);
        }
    }
}

// single block: exclusive scan of 782 bucket counts -> cb_start; init cursor = cb_start.
__global__ __launch_bounds__(1024) void bucket_scan_kernel(
        const int* __restrict__ bcnt, int* __restrict__ cb_start, int* __restrict__ cursor) {
    __shared__ int lds[1024];
    int t = threadIdx.x;
    int v = (t < NBUCK) ? bcnt[t] : 0;
    lds[t] = v;
    __syncthreads();
    for (int off = 1; off < 1024; off <<= 1) {
        int x = (t >= off) ? lds[t - off] : 0;
        __syncthreads();
        lds[t] += x;
        __syncthreads();
    }
    if (t < NBUCK) {
        int ex = lds[t] - v;
        cb_start[t] = ex;
        cursor[t] = ex;
    }
    if (t == NBUCK - 1) cb_start[NBUCK] = lds[t];
}

// coarse scatter: edge -> bucket-grouped tmp via per-bucket global cursor (order-free)
__global__ void coarse_scatter_kernel(const int* __restrict__ src, const int* __restrict__ dst,
                                      int* __restrict__ cursor,
                                      const float* __restrict__ edge_attr,
                                      int4* __restrict__ tmp,
                                      unsigned char* __restrict__ dstb) {
    int e = blockIdx.x * blockDim.x + threadIdx.x;
    if (e >= N_EDGES) return;
    int d = dst[e];
    int k = d >> BSH;
    int slot = atomicAdd(&cursor[k], 1);
    float4 ea = ((const float4*)edge_attr)[e];
    __half2 h01 = __floats2half2_rn(ea.x, ea.y);
    __half2 h23 = __floats2half2_rn(ea.z, ea.w);
    int4 ent;
    ent.x = src[e];
    ent.y = *reinterpret_cast<int*>(&h01);
    ent.z = *reinterpret_cast<int*>(&h23);
    ent.w = d;
    tmp[slot] = ent;
    dstb[slot] = (unsigned char)(d & (BNODES - 1));
}

// fine sort: one block per 64-node bucket (782 blocks); hist via 1B dstb side-array.
__global__ __launch_bounds__(256) void fine_sort_kernel(
        const int* __restrict__ cb_start, const int4* __restrict__ tmp,
        const unsigned char* __restrict__ dstb,
        int4* __restrict__ csr, int* __restrict__ srcs,
        int* __restrict__ row_start) {
    __shared__ int hist2[BNODES];
    __shared__ int cursor[BNODES];
    __shared__ int lds[BNODES];
    int k = blockIdx.x;
    int t = threadIdx.x;
    int beg = cb_start[k], end = cb_start[k + 1];
    if (t < BNODES) hist2[t] = 0;
    __syncthreads();
    for (int i = beg + t; i < end; i += 256)
        atomicAdd(&hist2[dstb[i]], 1);
    __syncthreads();
    int v = 0;
    if (t < BNODES) { v = hist2[t]; lds[t] = v; }
    __syncthreads();
    for (int off = 1; off < BNODES; off <<= 1) {
        int x = (t < BNODES && t >= off) ? lds[t - off] : 0;
        __syncthreads();
        if (t < BNODES) lds[t] += x;
        __syncthreads();
    }
    if (t < BNODES) {
        int pre = lds[t] - v;
        cursor[t] = pre;
        int node = (k << BSH) + t;
        if (node <= N_NODES) row_start[node] = beg + pre;
    }
    __syncthreads();
    for (int i = beg + t; i < end; i += 256) {
        int4 ent = tmp[i];
        int slot = beg + atomicAdd(&cursor[ent.w & (BNODES - 1)], 1);
        csr[slot] = ent;
        srcs[slot] = ent.x;
    }
}

// ---------------- layer-1 projection: lane = node, scalar weights ----------------
__global__ __launch_bounds__(256) void proj1_kernel(
        const float* __restrict__ xin,
        const __half2* __restrict__ wt,
        const float* __restrict__ bb,
        __half2* __restrict__ xlh, __half2* __restrict__ xrh) {
    int g = __builtin_amdgcn_readfirstlane((int)(threadIdx.x >> 6));
    int lane = threadIdx.x & 63;
    int node = blockIdx.x * 64 + lane;
    if (node >= N_NODES) return;

    h2v xrow[32];
    const float4* xp = (const float4*)(xin + node * 64);
#pragma unroll
    for (int q = 0; q < 16; ++q) {
        float4 v = xp[q];
        __half2 a = __floats2half2_rn(v.x, v.y);
        __half2 b = __floats2half2_rn(v.z, v.w);
        xrow[2 * q]     = *reinterpret_cast<h2v*>(&a);
        xrow[2 * q + 1] = *reinterpret_cast<h2v*>(&b);
    }

    __half2* outp = (g < 2) ? xlh : xrh;
    int chbase = g * 32;
    int localbase = (g & 1) * 16;

#pragma unroll
    for (int cp = 0; cp < 16; ++cp) {
        int ch0 = chbase + 2 * cp;
        const h2v* w0 = (const h2v*)(wt + ch0 * 32);
        const h2v* w1 = (const h2v*)(wt + (ch0 + 1) * 32);
        float a0 = bb[ch0], a1 = bb[ch0 + 1];
#pragma unroll
        for (int kk = 0; kk < 32; ++kk) {
            a0 = fdot2f(xrow[kk], w0[kk], a0);
            a1 = fdot2f(xrow[kk], w1[kk], a1);
        }
        outp[node * 32 + localbase + cp] = __floats2half2_rn(a0, a1);
    }
}

// ---------------- per-edge score: 4 lanes per edge (quarter-row cooperative gather) ----------------
__global__ __launch_bounds__(256) void score_kernel(
        const int4* __restrict__ csr,
        const __half2* __restrict__ xlh, const __half2* __restrict__ xrh,
        const __half2* __restrict__ weh, const __half2* __restrict__ atth,
        float* __restrict__ score) {
    __shared__ __half2 sweh[128];
    __shared__ __half2 satth[32];
    int t = threadIdx.x;
    if (t < 128) sweh[t] = weh[t];
    else if (t < 160) satth[t - 128] = atth[t - 128];
    __syncthreads();

    int e = blockIdx.x * 64 + (t >> 2);   // N_EDGES % 64 == 0
    int sub = t & 3;                      // channel chunk: half2 indices sub*8..sub*8+7
    int4 ent = csr[e];
    __half2 ea01 = *reinterpret_cast<__half2*>(&ent.y);
    __half2 ea23 = *reinterpret_cast<__half2*>(&ent.z);
    __half2 e0 = __half2half2(__low2half(ea01));
    __half2 e1 = __half2half2(__high2half(ea01));
    __half2 e2 = __half2half2(__low2half(ea23));
    __half2 e3 = __half2half2(__high2half(ea23));
    const h2v sl = { (_Float16)SLOPE, (_Float16)SLOPE };

    const int4* xa = (const int4*)(xlh + (size_t)ent.x * 32) + sub * 2;
    const int4* xb = (const int4*)(xrh + (size_t)ent.w * 32) + sub * 2;
    int4 va[2], vb[2];
    va[0] = xa[0]; va[1] = xa[1];
    vb[0] = xb[0]; vb[1] = xb[1];
    const __half2* ha = reinterpret_cast<const __half2*>(va);
    const __half2* hc = reinterpret_cast<const __half2*>(vb);

    float acc = 0.f;
#pragma unroll
    for (int j = 0; j < 8; ++j) {
        int c = sub * 8 + j;
        __half2 v2 = __hadd2(ha[j], hc[j]);
        v2 = __hfma2(e0, sweh[c * 4 + 0], v2);
        v2 = __hfma2(e1, sweh[c * 4 + 1], v2);
        v2 = __hfma2(e2, sweh[c * 4 + 2], v2);
        v2 = __hfma2(e3, sweh[c * 4 + 3], v2);
        h2v vv = *reinterpret_cast<h2v*>(&v2);
        h2v Lv = __builtin_elementwise_max(vv, sl * vv);   // v_pk_max_f16 leaky-relu
        __half2 av = satth[c];
        acc = fdot2f(Lv, *reinterpret_cast<h2v*>(&av), acc);
    }
    acc += __shfl_xor(acc, 1, 64);
    acc += __shfl_xor(acc, 2, 64);
    if (sub == 0) score[e] = acc;
}

// ---------------- aggregation v2: one wave per node, 16 lanes per edge ----------------
__global__ __launch_bounds__(256) void agg_kernel(
        const int* __restrict__ row_start,
        const int* __restrict__ srcs,
        const float* __restrict__ score,
        const __half2* __restrict__ xlh,
        const float* __restrict__ bias,
        float* __restrict__ out) {
    int wave = (blockIdx.x * blockDim.x + threadIdx.x) >> 6;
    if (wave >= N_NODES) return;
    int lane = threadIdx.x & 63;
    int q = lane & 15;            // channel quad: ch 4q..4q+3
    int grp = lane >> 4;          // edge subgroup 0..3
    int d = wave;
    int beg = __builtin_amdgcn_readfirstlane(row_start[d]);
    int end = __builtin_amdgcn_readfirstlane(row_start[d + 1]);

    const int2* xl2 = (const int2*)xlh;   // row = 16 int2 (4 ch each)

    float l_lane = 0.f;
    float a0 = 0.f, a1 = 0.f, a2 = 0.f, a3 = 0.f;

    for (int cbeg = beg; cbeg < end; cbeg += 64) {
        int n = end - cbeg;
        int nn = min(n, 64);
        // per-lane score + src (overreads land in mapped pad / following arrays)
        float sc = score[cbeg + lane];
        float p = __expf(sc);
        p = (lane < n) ? p : 0.f;
        l_lane += p;
        int sv = srcs[cbeg + lane];

        for (int j = 0; j < nn; j += 4) {
            int e = j + grp;
            bool ok = e < nn;
            int esel = ok ? e : 0;
            int s = __shfl(sv, esel, 64);          // ds_bpermute
            float pe = __shfl(p, esel, 64);
            pe = ok ? pe : 0.f;                    // zero contribution for tail groups
            int2 xw = xl2[(size_t)s * 16 + q];
            __half2 h0 = *reinterpret_cast<__half2*>(&xw.x);
            __half2 h1 = *reinterpret_cast<__half2*>(&xw.y);
            float2 f0 = __half22float2(h0);
            float2 f1 = __half22float2(h1);
            a0 += pe * f0.x; a1 += pe * f0.y;
            a2 += pe * f1.x; a3 += pe * f1.y;
        }
    }

    // reduce across the 4 edge subgroups (lane bits 4,5)
    a0 += __shfl_xor(a0, 16, 64); a0 += __shfl_xor(a0, 32, 64);
    a1 += __shfl_xor(a1, 16, 64); a1 += __shfl_xor(a1, 32, 64);
    a2 += __shfl_xor(a2, 16, 64); a2 += __shfl_xor(a2, 32, 64);
    a3 += __shfl_xor(a3, 16, 64); a3 += __shfl_xor(a3, 32, 64);
    float l = lane63_bcast(wave_sum_to63(l_lane));
    if (grp == 0) {
        float inv = 1.f / (l + 1e-16f);
        float4 b4 = ((const float4*)bias)[q];
        float o0 = a0 * inv + b4.x;
        float o1 = a1 * inv + b4.y;
        float o2 = a2 * inv + b4.z;
        float o3 = a3 * inv + b4.w;
        o0 = o0 > 0.f ? o0 : expm1f(o0);
        o1 = o1 > 0.f ? o1 : expm1f(o1);
        o2 = o2 > 0.f ? o2 : expm1f(o2);
        o3 = o3 > 0.f ? o3 : expm1f(o3);
        ((float4*)out)[d * 16 + q] = float4{o0, o1, o2, o3};
    }
}

// ---------------- fused pool + head: one block per graph ----------------
__global__ __launch_bounds__(256) void pool_head_kernel(
        const float* __restrict__ h, const int* __restrict__ batch,
        const float* __restrict__ fc1w, const float* __restrict__ fc1b,
        const float* __restrict__ fc2w, const float* __restrict__ fc2b,
        float* __restrict__ out) {
    int g = blockIdx.x;
    int lo = 0, hi = N_NODES;
    while (lo < hi) { int mid = (lo + hi) >> 1; if (batch[mid] < g) lo = mid + 1; else hi = mid; }
    int start = lo;
    hi = N_NODES;
    while (lo < hi) { int mid = (lo + hi) >> 1; if (batch[mid] < g + 1) lo = mid + 1; else hi = mid; }
    int end = lo;

    int lane = threadIdx.x & 63;
    int w = threadIdx.x >> 6;
    float s = 0.f;
    for (int n = start + w; n < end; n += 4) s += h[n * H + lane];
    __shared__ float red[4][H];
    __shared__ float gv[H];
    __shared__ float f[FC];
    __shared__ float lg[NC];
    red[w][lane] = s;
    __syncthreads();
    if (w == 0) {
        float tot = red[0][lane] + red[1][lane] + red[2][lane] + red[3][lane];
        gv[lane] = tot / fmaxf((float)(end - start), 1.f);
    }
    __syncthreads();
    int t = threadIdx.x;
    if (t < FC) {
        float acc = fc1b[t];
#pragma unroll 16
        for (int k = 0; k < H; ++k) acc += gv[k] * fc1w[k * FC + t];
        f[t] = fmaxf(acc, 0.f);
    }
    __syncthreads();
    if (t < NC) {
        float a = fc2b[t];
        for (int k = 0; k < FC; ++k) a += f[k] * fc2w[k * NC + t];
        lg[t] = a;
    }
    __syncthreads();
    if (t < NC) {
        float mx = fmaxf(lg[0], lg[1]);
        float lse = mx + logf(expf(lg[0] - mx) + expf(lg[1] - mx));
        out[g * NC + t] = lg[t] - lse;
    }
}

extern "C" void kernel_launch(void* const* d_in, const int* in_sizes, int n_in,
                              void* d_out, int out_size, void* d_ws, size_t ws_size,
                              hipStream_t stream) {
    const float* x         = (const float*)d_in[0];
    const int*   edge_idx  = (const int*)d_in[1];
    const float* edge_attr = (const float*)d_in[2];
    const int*   batch     = (const int*)d_in[3];
    const float* Wl0  = (const float*)d_in[4];
    const float* bl0  = (const float*)d_in[5];
    const float* Wr0  = (const float*)d_in[6];
    const float* br0  = (const float*)d_in[7];
    const float* We0  = (const float*)d_in[8];
    const float* att0 = (const float*)d_in[9];
    const float* bias0= (const float*)d_in[10];
    const float* Wl1  = (const float*)d_in[11];
    const float* bl1  = (const float*)d_in[12];
    const float* Wr1  = (const float*)d_in[13];
    const float* br1  = (const float*)d_in[14];
    const float* We1  = (const float*)d_in[15];
    const float* att1 = (const float*)d_in[16];
    const float* bias1= (const float*)d_in[17];
    const float* fc1w = (const float*)d_in[18];
    const float* fc1b = (const float*)d_in[19];
    const float* fc2w = (const float*)d_in[20];
    const float* fc2b = (const float*)d_in[21];

    // ---- workspace layout ----
    // tmp aliases [C | escore | pad] (tmp dead after fine_sort; C/escore written after).
    __half2* xlh    = (__half2*)d_ws;                 // [N*32]
    __half2* xrh    = xlh + N_NODES * 32;             // [N*32]
    float* C        = (float*)(xrh + N_NODES * 32);   // [N,64] fp32 ┐
    float* escore   = C + N_NODES * 64;               // [E]         ├ tmp aliases these
    float* pad      = escore + N_EDGES;               // [E]         ┘
    int4*  tmp      = (int4*)C;                       // [E]
    int4*  csr      = (int4*)(pad + N_EDGES);         // [E]
    int*   srcs     = (int*)(csr + N_EDGES);          // [E]
    int*   row_start= srcs + N_EDGES;                 // [N+1]
    unsigned char* dstb = (unsigned char*)(row_start + N_NODES + 1); // [E] bytes
    int*   bcnt     = (int*)(dstb + N_EDGES);         // [NBUCK]
    int*   cb_start = bcnt + NBUCK;                   // [NBUCK+1]
    int*   cursor   = cb_start + NBUCK + 1;           // [NBUCK]
    __half2* weh0   = (__half2*)(cursor + NBUCK);
    __half2* weh1   = weh0 + 128;
    __half2* wt1    = weh1 + 128;                     // [128*32]
    float* bb1      = (float*)(wt1 + 128 * 32);       // [128]
    __half2* atth0  = (__half2*)(bb1 + 128);          // [32]
    __half2* atth1  = atth0 + 32;                     // [32]

    const int* src = edge_idx;
    const int* dst = edge_idx + N_EDGES;

    const int edgeBlocks  = (N_EDGES + 255) / 256;
    const int scoreBlocks = N_EDGES / 64;             // 25000 (4 lanes/edge)
    const int waveBlocks  = (N_NODES * 64 + 255) / 256;
    const int p1Blocks    = (N_NODES + 63) / 64;
    const int frontBlocks = NB1 + PAIR_BLOCKS + 1;

    // ---- CSR build: bucket hist (LDS+flush) -> scan -> cursor scatter -> fine sort ----
    hipMemsetAsync(bcnt, 0, NBUCK * sizeof(int), stream);
    front_kernel<<<frontBlocks, 256, 0, stream>>>(dst, bcnt,
                                                  x, Wl0, bl0, Wr0, br0, xlh, xrh,
                                                  We0, We1, Wl1, bl1, Wr1, br1,
                                                  weh0, weh1, wt1, bb1,
                                                  att0, att1, atth0, atth1);
    bucket_scan_kernel<<<1, 1024, 0, stream>>>(bcnt, cb_start, cursor);
    coarse_scatter_kernel<<<edgeBlocks, 256, 0, stream>>>(src, dst, cursor,
                                                          edge_attr, tmp, dstb);
    fine_sort_kernel<<<NBUCK, 256, 0, stream>>>(cb_start, tmp, dstb, csr, srcs, row_start);

    // ---- layer 0 ----
    score_kernel<<<scoreBlocks, 256, 0, stream>>>(csr, xlh, xrh, weh0, atth0, escore);
    agg_kernel<<<waveBlocks, 256, 0, stream>>>(row_start, srcs, escore, xlh, bias0, C);

    // ---- layer 1 ----
    proj1_kernel<<<p1Blocks, 256, 0, stream>>>(C, wt1, bb1, xlh, xrh);
    score_kernel<<<scoreBlocks, 256, 0, stream>>>(csr, xlh, xrh, weh1, atth1, escore);
    agg_kernel<<<waveBlocks, 256, 0, stream>>>(row_start, srcs, escore, xlh, bias1, C);

    // ---- pool + head (fused) ----
    pool_head_kernel<<<G_GRAPHS, 256, 0, stream>>>(C, batch, fc1w, fc1b, fc2w, fc2b, (float*)d_out);
}

// Round 15
// 379.521 us; speedup vs baseline: 1.9208x; 1.9208x over previous
//
#include <hip/hip_runtime.h>
#include <hip/hip_fp16.h>

#define N_NODES 50000
#define N_EDGES 1600000
#define H 64
#define IN_CH 7
#define EDIM 4
#define G_GRAPHS 256
#define FC 128
#define NC 2
#define SLOPE 0.2f
#define BSH 6                           // bucket shift: 64 nodes per bucket
#define BNODES 64
#define NBUCK ((N_NODES + BNODES - 1) / BNODES)    // 782
#define EPB1 8192                       // edges per front hist block
#define NB1 ((N_EDGES + EPB1 - 1) / EPB1)          // 196
#define PAIR_BLOCKS ((N_NODES * 32 + 255) / 256)   // 6250

typedef _Float16 h2v __attribute__((ext_vector_type(2)));

__device__ __forceinline__ float fdot2f(h2v a, h2v b, float c) {
#if defined(__has_builtin) && __has_builtin(__builtin_amdgcn_fdot2)
    return __builtin_amdgcn_fdot2(a, b, c, false);
#else
    return c + (float)a[0] * (float)b[0] + (float)a[1] * (float)b[1];
#endif
}

// ---------------- DPP wave-64 reductions ----------------
__device__ __forceinline__ float wave_sum_to63(float x) {
    x += __int_as_float(__builtin_amdgcn_update_dpp(0, __float_as_int(x), 0x111, 0xf, 0xf, true)); // row_shr:1
    x += __int_as_float(__builtin_amdgcn_update_dpp(0, __float_as_int(x), 0x112, 0xf, 0xf, true)); // row_shr:2
    x += __int_as_float(__builtin_amdgcn_update_dpp(0, __float_as_int(x), 0x114, 0xf, 0xf, true)); // row_shr:4
    x += __int_as_float(__builtin_amdgcn_update_dpp(0, __float_as_int(x), 0x118, 0xf, 0xf, true)); // row_shr:8
    x += __int_as_float(__builtin_amdgcn_update_dpp(0, __float_as_int(x), 0x142, 0xf, 0xf, true)); // row_bcast:15
    x += __int_as_float(__builtin_amdgcn_update_dpp(0, __float_as_int(x), 0x143, 0xf, 0xf, true)); // row_bcast:31
    return x;
}
__device__ __forceinline__ float lane63_bcast(float x) {
    return __int_as_float(__builtin_amdgcn_readlane(__float_as_int(x), 63));
}

// ---------------- fused front-end: coarse histogram+rank (LDS atomics) + proj0 + prep ----------------
__global__ __launch_bounds__(256) void front_kernel(
        const int* __restrict__ dst, int* __restrict__ rank1, int* __restrict__ bhist,
        const float* __restrict__ xin,
        const float* __restrict__ Wl0, const float* __restrict__ bl0,
        const float* __restrict__ Wr0, const float* __restrict__ br0,
        __half2* __restrict__ xlh, __half2* __restrict__ xrh,
        const float* __restrict__ We0, const float* __restrict__ We1,
        const float* __restrict__ Wl1, const float* __restrict__ bl1,
        const float* __restrict__ Wr1, const float* __restrict__ br1,
        __half2* __restrict__ weh0, __half2* __restrict__ weh1,
        __half2* __restrict__ wt, float* __restrict__ bb,
        const float* __restrict__ att0, const float* __restrict__ att1,
        __half2* __restrict__ atth0, __half2* __restrict__ atth1) {
    __shared__ int hist[NBUCK];
    int b = blockIdx.x;
    int t = threadIdx.x;
    if (b < NB1) {
        for (int i = t; i < NBUCK; i += 256) hist[i] = 0;
        __syncthreads();
#pragma unroll
        for (int i = 0; i < EPB1 / 256; ++i) {
            int e = b * EPB1 + i * 256 + t;
            if (e < N_EDGES) {
                int k = dst[e] >> BSH;
                rank1[e] = atomicAdd(&hist[k], 1);
            }
        }
        __syncthreads();
        for (int i = t; i < NBUCK; i += 256) bhist[b * NBUCK + i] = hist[i];
    } else if (b < NB1 + PAIR_BLOCKS) {
        int idx = (b - NB1) * 256 + t;
        if (idx < N_NODES * 32) {
            int n = idx >> 5;
            int c = idx & 31;
            const float* xi = xin + n * IN_CH;
            float2 bl2 = ((const float2*)bl0)[c];
            float2 br2 = ((const float2*)br0)[c];
            float al0 = bl2.x, al1 = bl2.y, ar0 = br2.x, ar1 = br2.y;
#pragma unroll
            for (int k = 0; k < IN_CH; ++k) {
                float xv = xi[k];
                float2 wl2 = ((const float2*)(Wl0 + k * H))[c];
                float2 wr2 = ((const float2*)(Wr0 + k * H))[c];
                al0 += xv * wl2.x; al1 += xv * wl2.y;
                ar0 += xv * wr2.x; ar1 += xv * wr2.y;
            }
            xlh[idx] = __floats2half2_rn(al0, al1);
            xrh[idx] = __floats2half2_rn(ar0, ar1);
        }
    } else {
        if (t < 32) {
            for (int k = 0; k < 4; ++k)
                weh0[t * 4 + k] = __floats2half2_rn(We0[k * H + 2 * t], We0[k * H + 2 * t + 1]);
        } else if (t < 64) {
            int c = t - 32;
            for (int k = 0; k < 4; ++k)
                weh1[c * 4 + k] = __floats2half2_rn(We1[k * H + 2 * c], We1[k * H + 2 * c + 1]);
        }
        if (t < 128) {
            const float* W = (t < 64) ? Wl1 : Wr1;
            int c = t & 63;
            for (int kk = 0; kk < 32; ++kk)
                wt[t * 32 + kk] = __floats2half2_rn(W[(2 * kk) * H + c], W[(2 * kk + 1) * H + c]);
            bb[t] = (t < 64) ? bl1[c] : br1[c];
        } else if (t < 160) {
            int c = t - 128;
            atth0[c] = __floats2half2_rn(att0[2 * c], att0[2 * c + 1]);
            atth1[c] = __floats2half2_rn(att1[2 * c], att1[2 * c + 1]);
        }
    }
}

// scan A: one block per bucket k; exclusive scan of bhist[b][k] over the 196 front
// blocks -> bases[b][k], total -> btot[k]. All buckets in parallel.
__global__ __launch_bounds__(256) void scan_a_kernel(
        const int* __restrict__ bhist, int* __restrict__ bases, int* __restrict__ btot) {
    __shared__ int lds[256];
    int k = blockIdx.x;
    int t = threadIdx.x;
    int v = (t < NB1) ? bhist[t * NBUCK + k] : 0;
    lds[t] = v;
    __syncthreads();
    for (int off = 1; off < 256; off <<= 1) {
        int x = (t >= off) ? lds[t - off] : 0;
        __syncthreads();
        lds[t] += x;
        __syncthreads();
    }
    if (t < NB1) bases[t * NBUCK + k] = lds[t] - v;
    if (t == NB1 - 1) btot[k] = lds[t];
}

// scan B: single block, exclusive scan of 782 bucket totals -> cb_start.
__global__ __launch_bounds__(1024) void scan_b_kernel(
        const int* __restrict__ btot, int* __restrict__ cb_start) {
    __shared__ int lds[1024];
    int t = threadIdx.x;
    int v = (t < NBUCK) ? btot[t] : 0;
    lds[t] = v;
    __syncthreads();
    for (int off = 1; off < 1024; off <<= 1) {
        int x = (t >= off) ? lds[t - off] : 0;
        __syncthreads();
        lds[t] += x;
        __syncthreads();
    }
    if (t < NBUCK) cb_start[t] = lds[t] - v;
    if (t == NBUCK - 1) cb_start[NBUCK] = lds[t];
}

// coarse scatter: edge -> bucket-sorted tmp (block-sequential slots within bucket);
// also emits 1B dst-low byte side-array for fine_sort's histogram pass.
__global__ void coarse_scatter_kernel(const int* __restrict__ src, const int* __restrict__ dst,
                                      const int* __restrict__ rank1, const int* __restrict__ bases,
                                      const int* __restrict__ cb_start,
                                      const float* __restrict__ edge_attr,
                                      int4* __restrict__ tmp,
                                      unsigned char* __restrict__ dstb) {
    int e = blockIdx.x * blockDim.x + threadIdx.x;
    if (e >= N_EDGES) return;
    int d = dst[e];
    int k = d >> BSH;
    int b = e / EPB1;
    int slot = cb_start[k] + bases[b * NBUCK + k] + rank1[e];
    float4 ea = ((const float4*)edge_attr)[e];
    __half2 h01 = __floats2half2_rn(ea.x, ea.y);
    __half2 h23 = __floats2half2_rn(ea.z, ea.w);
    int4 ent;
    ent.x = src[e];
    ent.y = *reinterpret_cast<int*>(&h01);
    ent.z = *reinterpret_cast<int*>(&h23);
    ent.w = d;
    tmp[slot] = ent;
    dstb[slot] = (unsigned char)(d & (BNODES - 1));
}

// fine sort: one block per 64-node bucket (782 blocks); hist via 1B dstb side-array.
__global__ __launch_bounds__(256) void fine_sort_kernel(
        const int* __restrict__ cb_start, const int4* __restrict__ tmp,
        const unsigned char* __restrict__ dstb,
        int4* __restrict__ csr, int* __restrict__ srcs,
        int* __restrict__ row_start) {
    __shared__ int hist2[BNODES];
    __shared__ int cursor[BNODES];
    __shared__ int lds[BNODES];
    int k = blockIdx.x;
    int t = threadIdx.x;
    int beg = cb_start[k], end = cb_start[k + 1];
    if (t < BNODES) hist2[t] = 0;
    __syncthreads();
    for (int i = beg + t; i < end; i += 256)
        atomicAdd(&hist2[dstb[i]], 1);
    __syncthreads();
    int v = 0;
    if (t < BNODES) { v = hist2[t]; lds[t] = v; }
    __syncthreads();
    for (int off = 1; off < BNODES; off <<= 1) {
        int x = (t < BNODES && t >= off) ? lds[t - off] : 0;
        __syncthreads();
        if (t < BNODES) lds[t] += x;
        __syncthreads();
    }
    if (t < BNODES) {
        int pre = lds[t] - v;
        cursor[t] = pre;
        int node = (k << BSH) + t;
        if (node <= N_NODES) row_start[node] = beg + pre;
    }
    __syncthreads();
    for (int i = beg + t; i < end; i += 256) {
        int4 ent = tmp[i];
        int slot = beg + atomicAdd(&cursor[ent.w & (BNODES - 1)], 1);
        csr[slot] = ent;
        srcs[slot] = ent.x;
    }
}

// ---------------- layer-1 projection: lane = node, scalar weights ----------------
__global__ __launch_bounds__(256) void proj1_kernel(
        const float* __restrict__ xin,
        const __half2* __restrict__ wt,
        const float* __restrict__ bb,
        __half2* __restrict__ xlh, __half2* __restrict__ xrh) {
    int g = __builtin_amdgcn_readfirstlane((int)(threadIdx.x >> 6));
    int lane = threadIdx.x & 63;
    int node = blockIdx.x * 64 + lane;
    if (node >= N_NODES) return;

    h2v xrow[32];
    const float4* xp = (const float4*)(xin + node * 64);
#pragma unroll
    for (int q = 0; q < 16; ++q) {
        float4 v = xp[q];
        __half2 a = __floats2half2_rn(v.x, v.y);
        __half2 b = __floats2half2_rn(v.z, v.w);
        xrow[2 * q]     = *reinterpret_cast<h2v*>(&a);
        xrow[2 * q + 1] = *reinterpret_cast<h2v*>(&b);
    }

    __half2* outp = (g < 2) ? xlh : xrh;
    int chbase = g * 32;
    int localbase = (g & 1) * 16;

#pragma unroll
    for (int cp = 0; cp < 16; ++cp) {
        int ch0 = chbase + 2 * cp;
        const h2v* w0 = (const h2v*)(wt + ch0 * 32);
        const h2v* w1 = (const h2v*)(wt + (ch0 + 1) * 32);
        float a0 = bb[ch0], a1 = bb[ch0 + 1];
#pragma unroll
        for (int kk = 0; kk < 32; ++kk) {
            a0 = fdot2f(xrow[kk], w0[kk], a0);
            a1 = fdot2f(xrow[kk], w1[kk], a1);
        }
        outp[node * 32 + localbase + cp] = __floats2half2_rn(a0, a1);
    }
}

// ---------------- per-edge score: 4 lanes per edge (quarter-row cooperative gather) ----------------
__global__ __launch_bounds__(256) void score_kernel(
        const int4* __restrict__ csr,
        const __half2* __restrict__ xlh, const __half2* __restrict__ xrh,
        const __half2* __restrict__ weh, const __half2* __restrict__ atth,
        float* __restrict__ score) {
    __shared__ __half2 sweh[128];
    __shared__ __half2 satth[32];
    int t = threadIdx.x;
    if (t < 128) sweh[t] = weh[t];
    else if (t < 160) satth[t - 128] = atth[t - 128];
    __syncthreads();

    int e = blockIdx.x * 64 + (t >> 2);   // N_EDGES % 64 == 0
    int sub = t & 3;                      // channel chunk: half2 indices sub*8..sub*8+7
    int4 ent = csr[e];
    __half2 ea01 = *reinterpret_cast<__half2*>(&ent.y);
    __half2 ea23 = *reinterpret_cast<__half2*>(&ent.z);
    __half2 e0 = __half2half2(__low2half(ea01));
    __half2 e1 = __half2half2(__high2half(ea01));
    __half2 e2 = __half2half2(__low2half(ea23));
    __half2 e3 = __half2half2(__high2half(ea23));
    const h2v sl = { (_Float16)SLOPE, (_Float16)SLOPE };

    const int4* xa = (const int4*)(xlh + (size_t)ent.x * 32) + sub * 2;
    const int4* xb = (const int4*)(xrh + (size_t)ent.w * 32) + sub * 2;
    int4 va[2], vb[2];
    va[0] = xa[0]; va[1] = xa[1];
    vb[0] = xb[0]; vb[1] = xb[1];
    const __half2* ha = reinterpret_cast<const __half2*>(va);
    const __half2* hc = reinterpret_cast<const __half2*>(vb);

    float acc = 0.f;
#pragma unroll
    for (int j = 0; j < 8; ++j) {
        int c = sub * 8 + j;
        __half2 v2 = __hadd2(ha[j], hc[j]);
        v2 = __hfma2(e0, sweh[c * 4 + 0], v2);
        v2 = __hfma2(e1, sweh[c * 4 + 1], v2);
        v2 = __hfma2(e2, sweh[c * 4 + 2], v2);
        v2 = __hfma2(e3, sweh[c * 4 + 3], v2);
        h2v vv = *reinterpret_cast<h2v*>(&v2);
        h2v Lv = __builtin_elementwise_max(vv, sl * vv);   // v_pk_max_f16 leaky-relu
        __half2 av = satth[c];
        acc = fdot2f(Lv, *reinterpret_cast<h2v*>(&av), acc);
    }
    acc += __shfl_xor(acc, 1, 64);
    acc += __shfl_xor(acc, 2, 64);
    if (sub == 0) score[e] = acc;
}

// ---------------- aggregation v2: one wave per node, 16 lanes per edge ----------------
__global__ __launch_bounds__(256) void agg_kernel(
        const int* __restrict__ row_start,
        const int* __restrict__ srcs,
        const float* __restrict__ score,
        const __half2* __restrict__ xlh,
        const float* __restrict__ bias,
        float* __restrict__ out) {
    int wave = (blockIdx.x * blockDim.x + threadIdx.x) >> 6;
    if (wave >= N_NODES) return;
    int lane = threadIdx.x & 63;
    int q = lane & 15;            // channel quad: ch 4q..4q+3
    int grp = lane >> 4;          // edge subgroup 0..3
    int d = wave;
    int beg = __builtin_amdgcn_readfirstlane(row_start[d]);
    int end = __builtin_amdgcn_readfirstlane(row_start[d + 1]);

    const int2* xl2 = (const int2*)xlh;   // row = 16 int2 (4 ch each)

    float l_lane = 0.f;
    float a0 = 0.f, a1 = 0.f, a2 = 0.f, a3 = 0.f;

    for (int cbeg = beg; cbeg < end; cbeg += 64) {
        int n = end - cbeg;
        int nn = min(n, 64);
        // per-lane score + src (overreads land in mapped pad / following arrays)
        float sc = score[cbeg + lane];
        float p = __expf(sc);
        p = (lane < n) ? p : 0.f;
        l_lane += p;
        int sv = srcs[cbeg + lane];

        for (int j = 0; j < nn; j += 4) {
            int e = j + grp;
            bool ok = e < nn;
            int esel = ok ? e : 0;
            int s = __shfl(sv, esel, 64);          // ds_bpermute
            float pe = __shfl(p, esel, 64);
            pe = ok ? pe : 0.f;                    // zero contribution for tail groups
            int2 xw = xl2[(size_t)s * 16 + q];
            __half2 h0 = *reinterpret_cast<__half2*>(&xw.x);
            __half2 h1 = *reinterpret_cast<__half2*>(&xw.y);
            float2 f0 = __half22float2(h0);
            float2 f1 = __half22float2(h1);
            a0 += pe * f0.x; a1 += pe * f0.y;
            a2 += pe * f1.x; a3 += pe * f1.y;
        }
    }

    // reduce across the 4 edge subgroups (lane bits 4,5)
    a0 += __shfl_xor(a0, 16, 64); a0 += __shfl_xor(a0, 32, 64);
    a1 += __shfl_xor(a1, 16, 64); a1 += __shfl_xor(a1, 32, 64);
    a2 += __shfl_xor(a2, 16, 64); a2 += __shfl_xor(a2, 32, 64);
    a3 += __shfl_xor(a3, 16, 64); a3 += __shfl_xor(a3, 32, 64);
    float l = lane63_bcast(wave_sum_to63(l_lane));
    if (grp == 0) {
        float inv = 1.f / (l + 1e-16f);
        float4 b4 = ((const float4*)bias)[q];
        float o0 = a0 * inv + b4.x;
        float o1 = a1 * inv + b4.y;
        float o2 = a2 * inv + b4.z;
        float o3 = a3 * inv + b4.w;
        o0 = o0 > 0.f ? o0 : expm1f(o0);
        o1 = o1 > 0.f ? o1 : expm1f(o1);
        o2 = o2 > 0.f ? o2 : expm1f(o2);
        o3 = o3 > 0.f ? o3 : expm1f(o3);
        ((float4*)out)[d * 16 + q] = float4{o0, o1, o2, o3};
    }
}

// ---------------- fused pool + head: one block per graph ----------------
__global__ __launch_bounds__(256) void pool_head_kernel(
        const float* __restrict__ h, const int* __restrict__ batch,
        const float* __restrict__ fc1w, const float* __restrict__ fc1b,
        const float* __restrict__ fc2w, const float* __restrict__ fc2b,
        float* __restrict__ out) {
    int g = blockIdx.x;
    int lo = 0, hi = N_NODES;
    while (lo < hi) { int mid = (lo + hi) >> 1; if (batch[mid] < g) lo = mid + 1; else hi = mid; }
    int start = lo;
    hi = N_NODES;
    while (lo < hi) { int mid = (lo + hi) >> 1; if (batch[mid] < g + 1) lo = mid + 1; else hi = mid; }
    int end = lo;

    int lane = threadIdx.x & 63;
    int w = threadIdx.x >> 6;
    float s = 0.f;
    for (int n = start + w; n < end; n += 4) s += h[n * H + lane];
    __shared__ float red[4][H];
    __shared__ float gv[H];
    __shared__ float f[FC];
    __shared__ float lg[NC];
    red[w][lane] = s;
    __syncthreads();
    if (w == 0) {
        float tot = red[0][lane] + red[1][lane] + red[2][lane] + red[3][lane];
        gv[lane] = tot / fmaxf((float)(end - start), 1.f);
    }
    __syncthreads();
    int t = threadIdx.x;
    if (t < FC) {
        float acc = fc1b[t];
#pragma unroll 16
        for (int k = 0; k < H; ++k) acc += gv[k] * fc1w[k * FC + t];
        f[t] = fmaxf(acc, 0.f);
    }
    __syncthreads();
    if (t < NC) {
        float a = fc2b[t];
        for (int k = 0; k < FC; ++k) a += f[k] * fc2w[k * NC + t];
        lg[t] = a;
    }
    __syncthreads();
    if (t < NC) {
        float mx = fmaxf(lg[0], lg[1]);
        float lse = mx + logf(expf(lg[0] - mx) + expf(lg[1] - mx));
        out[g * NC + t] = lg[t] - lse;
    }
}

extern "C" void kernel_launch(void* const* d_in, const int* in_sizes, int n_in,
                              void* d_out, int out_size, void* d_ws, size_t ws_size,
                              hipStream_t stream) {
    const float* x         = (const float*)d_in[0];
    const int*   edge_idx  = (const int*)d_in[1];
    const float* edge_attr = (const float*)d_in[2];
    const int*   batch     = (const int*)d_in[3];
    const float* Wl0  = (const float*)d_in[4];
    const float* bl0  = (const float*)d_in[5];
    const float* Wr0  = (const float*)d_in[6];
    const float* br0  = (const float*)d_in[7];
    const float* We0  = (const float*)d_in[8];
    const float* att0 = (const float*)d_in[9];
    const float* bias0= (const float*)d_in[10];
    const float* Wl1  = (const float*)d_in[11];
    const float* bl1  = (const float*)d_in[12];
    const float* Wr1  = (const float*)d_in[13];
    const float* br1  = (const float*)d_in[14];
    const float* We1  = (const float*)d_in[15];
    const float* att1 = (const float*)d_in[16];
    const float* bias1= (const float*)d_in[17];
    const float* fc1w = (const float*)d_in[18];
    const float* fc1b = (const float*)d_in[19];
    const float* fc2w = (const float*)d_in[20];
    const float* fc2b = (const float*)d_in[21];

    // ---- workspace layout ----
    // tmp aliases [C | escore | pad] (tmp dead after fine_sort; C/escore written after).
    __half2* xlh    = (__half2*)d_ws;                 // [N*32]
    __half2* xrh    = xlh + N_NODES * 32;             // [N*32]
    float* C        = (float*)(xrh + N_NODES * 32);   // [N,64] fp32 ┐
    float* escore   = C + N_NODES * 64;               // [E]         ├ tmp aliases these
    float* pad      = escore + N_EDGES;               // [E]         ┘
    int4*  tmp      = (int4*)C;                       // [E]
    int4*  csr      = (int4*)(pad + N_EDGES);         // [E]
    int*   srcs     = (int*)(csr + N_EDGES);          // [E]
    int*   row_start= srcs + N_EDGES;                 // [N+1]
    int*   rank1    = row_start + N_NODES + 1;        // [E]
    int*   bhist    = rank1 + N_EDGES;                // [NB1*NBUCK]
    int*   bases    = bhist + NB1 * NBUCK;            // [NB1*NBUCK]
    int*   btot     = bases + NB1 * NBUCK;            // [NBUCK]
    int*   cb_start = btot + NBUCK;                   // [NBUCK+1]
    unsigned char* dstb = (unsigned char*)(cb_start + NBUCK + 1); // [E] bytes
    __half2* weh0   = (__half2*)(dstb + N_EDGES);
    __half2* weh1   = weh0 + 128;
    __half2* wt1    = weh1 + 128;                     // [128*32]
    float* bb1      = (float*)(wt1 + 128 * 32);       // [128]
    __half2* atth0  = (__half2*)(bb1 + 128);          // [32]
    __half2* atth1  = atth0 + 32;                     // [32]

    const int* src = edge_idx;
    const int* dst = edge_idx + N_EDGES;

    const int edgeBlocks  = (N_EDGES + 255) / 256;
    const int scoreBlocks = N_EDGES / 64;             // 25000 (4 lanes/edge)
    const int waveBlocks  = (N_NODES * 64 + 255) / 256;
    const int p1Blocks    = (N_NODES + 63) / 64;
    const int frontBlocks = NB1 + PAIR_BLOCKS + 1;

    // ---- CSR build via 2-pass radix (LDS atomics, parallel scans) + proj0 + prep ----
    front_kernel<<<frontBlocks, 256, 0, stream>>>(dst, rank1, bhist,
                                                  x, Wl0, bl0, Wr0, br0, xlh, xrh,
                                                  We0, We1, Wl1, bl1, Wr1, br1,
                                                  weh0, weh1, wt1, bb1,
                                                  att0, att1, atth0, atth1);
    scan_a_kernel<<<NBUCK, 256, 0, stream>>>(bhist, bases, btot);
    scan_b_kernel<<<1, 1024, 0, stream>>>(btot, cb_start);
    coarse_scatter_kernel<<<edgeBlocks, 256, 0, stream>>>(src, dst, rank1, bases, cb_start,
                                                          edge_attr, tmp, dstb);
    fine_sort_kernel<<<NBUCK, 256, 0, stream>>>(cb_start, tmp, dstb, csr, srcs, row_start);

    // ---- layer 0 ----
    score_kernel<<<scoreBlocks, 256, 0, stream>>>(csr, xlh, xrh, weh0, atth0, escore);
    agg_kernel<<<waveBlocks, 256, 0, stream>>>(row_start, srcs, escore, xlh, bias0, C);

    // ---- layer 1 ----
    proj1_kernel<<<p1Blocks, 256, 0, stream>>>(C, wt1, bb1, xlh, xrh);
    score_kernel<<<scoreBlocks, 256, 0, stream>>>(csr, xlh, xrh, weh1, atth1, escore);
    agg_kernel<<<waveBlocks, 256, 0, stream>>>(row_start, srcs, escore, xlh, bias1, C);

    // ---- pool + head (fused) ----
    pool_head_kernel<<<G_GRAPHS, 256, 0, stream>>>(C, batch, fc1w, fc1b, fc2w, fc2b, (float*)d_out);
}